// Round 6
// baseline (109.225 us; speedup 1.0000x reference)
//
#include <hip/hip_runtime.h>

#define C    21
#define HW4  65536     // float4 groups per 512x512 plane
#define G    4         // groups per thread, laid out so a wave reads 4KB contiguous/channel

typedef float f4 __attribute__((ext_vector_type(4)));
typedef int   i4 __attribute__((ext_vector_type(4)));

// Block: 256 threads x 4 groups = 1024 groups = 16 KB window per channel plane.
// Wave w covers a contiguous 4 KB run per channel visit (4 back-to-back 1 KB loads,
// immediate-offset folded). Grid = 16 images x 64 windows = 1024 blocks.
__global__ __launch_bounds__(256) void iou_hist_kernel(
    const f4* __restrict__ pred, const i4* __restrict__ tgt,
    unsigned int* __restrict__ hist) {
  __shared__ unsigned int sh[3 * C];
  const int tid = threadIdx.x;
  if (tid < 3 * C) sh[tid] = 0;
  __syncthreads();

  const int lane = tid & 63;
  const int wv   = tid >> 6;
  const int bid  = blockIdx.x;
  const int b    = bid >> 6;                 // image index (64 blocks per image)
  const int win  = (bid & 63) << 10;         // window start (groups) within plane
  const int goff = win + (wv << 8) + lane;   // this thread's j=0 group in plane
  const int base = ((b * C) << 16) + goff;   // f4 index of channel 0

  // ---- argmax over 21 channels for 16 pixels (4 groups), channel-major ----
  f4 best[G]; i4 idx[G];
#pragma unroll
  for (int j = 0; j < G; ++j) {
    best[j] = pred[base + (j << 6)];         // channel 0
    idx[j]  = (i4)0;
  }
#pragma unroll
  for (int c = 1; c < C; ++c) {
    f4 v[G];
#pragma unroll
    for (int j = 0; j < G; ++j)
      v[j] = pred[base + (c << 16) + (j << 6)];
#pragma unroll
    for (int j = 0; j < G; ++j)
#pragma unroll
      for (int e = 0; e < 4; ++e)
        if (v[j][e] > best[j][e]) { best[j][e] = v[j][e]; idx[j][e] = c; }
  }

  // ---- targets ----
  i4 tg[G];
#pragma unroll
  for (int j = 0; j < G; ++j) tg[j] = tgt[(b << 16) + goff + (j << 6)];

  // ---- per-wave ballot histogram: lane c owns class c ----
  unsigned long long m[G * 4];
#pragma unroll
  for (int j = 0; j < G; ++j)
#pragma unroll
    for (int e = 0; e < 4; ++e)
      m[j * 4 + e] = __ballot(idx[j][e] == tg[j][e]);

  unsigned int cp = 0, ct = 0, ci = 0;
#pragma unroll
  for (int c = 0; c < C; ++c) {
    unsigned int np_ = 0, nt_ = 0, ni_ = 0;
#pragma unroll
    for (int j = 0; j < G; ++j)
#pragma unroll
      for (int e = 0; e < 4; ++e) {
        const unsigned long long pb = __ballot(idx[j][e] == c);
        np_ += (unsigned)__popcll(pb);
        ni_ += (unsigned)__popcll(pb & m[j * 4 + e]);
        nt_ += (unsigned)__popcll(__ballot(tg[j][e] == c));
      }
    if (lane == c) { cp = np_; ct = nt_; ci = ni_; }
  }

  // ---- wave -> block (LDS), block -> global ----
  if (lane < C) {
    atomicAdd(&sh[lane], cp);
    atomicAdd(&sh[C + lane], ct);
    atomicAdd(&sh[2 * C + lane], ci);
  }
  __syncthreads();
  if (tid < 3 * C) atomicAdd(&hist[tid], sh[tid]);
}

__global__ __launch_bounds__(64) void iou_finalize_kernel(
    const unsigned int* __restrict__ hist, float* __restrict__ out) {
  const int lane = threadIdx.x;
  float iou = 0.0f;
  if (lane < C) {
    const float p = (float)hist[lane];
    const float t = (float)hist[C + lane];
    const float i = (float)hist[2 * C + lane];
    const float u = p + t - i;
    iou = (u > 0.0f) ? (i / (u + 1e-6f)) : 0.0f;
  }
#pragma unroll
  for (int off = 32; off > 0; off >>= 1) iou += __shfl_down(iou, off);
  if (lane == 0) out[0] = iou / (float)C;
}

extern "C" void kernel_launch(void* const* d_in, const int* in_sizes, int n_in,
                              void* d_out, int out_size, void* d_ws, size_t ws_size,
                              hipStream_t stream) {
  const f4* pred = (const f4*)d_in[0];
  const i4* tgt  = (const i4*)d_in[1];
  float*    out  = (float*)d_out;
  unsigned int* hist = (unsigned int*)d_ws;

  // counters must start at zero every call (ws poisoned once, never re-poisoned)
  hipMemsetAsync(d_ws, 0, 3 * C * sizeof(unsigned int), stream);

  iou_hist_kernel<<<1024, 256, 0, stream>>>(pred, tgt, hist);
  iou_finalize_kernel<<<1, 64, 0, stream>>>(hist, out);
}